// Round 1
// baseline (78.199 us; speedup 1.0000x reference)
//
#include <hip/hip_runtime.h>

#define B_   32
#define N_   1024
#define DIM_ 512

// Kernel 1: per-batch inclusive scan of durations -> scatter phoneme index
// per output frame into idx_map (B*T int32). Frames >= total get -1.
__global__ void build_idx_kernel(const int* __restrict__ durations,
                                 int* __restrict__ idx_map, int T) {
    __shared__ int s[N_];
    const int b   = blockIdx.x;
    const int tid = threadIdx.x;
    const int d   = durations[b * N_ + tid];
    s[tid] = d;
    __syncthreads();
    // Hillis-Steele inclusive scan over 1024 elements
    for (int off = 1; off < N_; off <<= 1) {
        int v = (tid >= off) ? s[tid - off] : 0;
        __syncthreads();
        s[tid] += v;
        __syncthreads();
    }
    const int end   = s[tid];        // cum[tid]
    const int start = end - d;       // cum[tid-1]
    const int total = s[N_ - 1];

    int* row = idx_map + (size_t)b * T;
    // searchsorted(cum, t, 'right') == tid  for t in [start, end)
    for (int t = start; t < end; ++t) row[t] = tid;
    // invalid tail frames
    for (int t = total + tid; t < T; t += N_) row[t] = -1;
}

// Kernel 2: one block per output row (b,t): copy 512-float row via float4,
// zeros if invalid. Thread 0 writes the mask float.
__global__ void expand_kernel(const float* __restrict__ enc,
                              const int* __restrict__ idx_map,
                              float* __restrict__ out,
                              float* __restrict__ mask_out, int T) {
    const int row = blockIdx.x;          // b*T + t
    const int b   = row / T;
    const int idx = idx_map[row];
    float4* orow = (float4*)(out + (size_t)row * DIM_);
    if (idx >= 0) {
        const float4* irow =
            (const float4*)(enc + ((size_t)b * N_ + idx) * DIM_);
        orow[threadIdx.x] = irow[threadIdx.x];
    } else {
        orow[threadIdx.x] = make_float4(0.f, 0.f, 0.f, 0.f);
    }
    if (threadIdx.x == 0) mask_out[row] = (idx >= 0) ? 1.0f : 0.0f;
}

extern "C" void kernel_launch(void* const* d_in, const int* in_sizes, int n_in,
                              void* d_out, int out_size, void* d_ws, size_t ws_size,
                              hipStream_t stream) {
    const float* enc = (const float*)d_in[0];   // (B, N, DIM) f32
    const int*   dur = (const int*)d_in[1];     // (B, N) int
    // out = expanded (B*T*DIM) ++ mask (B*T)  => out_size = B*T*(DIM+1)
    const int T = out_size / (B_ * (DIM_ + 1));

    int*   idx_map  = (int*)d_ws;               // B*T int32
    float* out      = (float*)d_out;
    float* mask_out = out + (size_t)B_ * T * DIM_;

    build_idx_kernel<<<B_, N_, 0, stream>>>(dur, idx_map, T);
    expand_kernel<<<B_ * T, DIM_ / 4, 0, stream>>>(enc, idx_map, out, mask_out, T);
}

// Round 3
// 71.587 us; speedup vs baseline: 1.0924x; 1.0924x over previous
//
#include <hip/hip_runtime.h>

#define B_   32
#define N_   1024
#define DIM_ 512
#define F4_PER_ROW (DIM_ / 4)   // 128

typedef float f32x4 __attribute__((ext_vector_type(4)));

// Kernel 1: per-batch inclusive scan of durations -> scatter GLOBAL source
// row (b*N + phoneme) per output frame into idx_map (B*T int32). Invalid
// tail frames get -1.
__global__ void build_idx_kernel(const int* __restrict__ durations,
                                 int* __restrict__ idx_map, int T) {
    __shared__ int s[N_];
    const int b   = blockIdx.x;
    const int tid = threadIdx.x;
    const int d   = durations[b * N_ + tid];
    s[tid] = d;
    __syncthreads();
    // Hillis-Steele inclusive scan over 1024 elements
    for (int off = 1; off < N_; off <<= 1) {
        int v = (tid >= off) ? s[tid - off] : 0;
        __syncthreads();
        s[tid] += v;
        __syncthreads();
    }
    const int end   = s[tid];        // cum[tid]
    const int start = end - d;       // cum[tid-1]
    const int total = s[N_ - 1];

    int* row = idx_map + (size_t)b * T;
    const int g = b * N_ + tid;      // global source row
    for (int t = start; t < end; ++t) row[t] = g;
    for (int t = total + tid; t < T; t += N_) row[t] = -1;
}

// Kernel 2: grid-stride over all output float4s. row = i>>7, lane = i&127.
// Nontemporal stores for the write-once output stream.
__global__ void expand_kernel(const f32x4* __restrict__ enc4,
                              const int* __restrict__ idx_map,
                              f32x4* __restrict__ out4,
                              float* __restrict__ mask_out, long nf4) {
    long i = (long)blockIdx.x * blockDim.x + threadIdx.x;
    const long stride = (long)gridDim.x * blockDim.x;
    const f32x4 zero = {0.f, 0.f, 0.f, 0.f};
    for (; i < nf4; i += stride) {
        const int row  = (int)(i >> 7);
        const int lane = (int)(i & (F4_PER_ROW - 1));
        const int g    = idx_map[row];          // global source row or -1
        f32x4 v = zero;
        if (g >= 0) v = enc4[(long)g * F4_PER_ROW + lane];
        __builtin_nontemporal_store(v, &out4[i]);
        if (lane == 0)
            __builtin_nontemporal_store(g >= 0 ? 1.0f : 0.0f, &mask_out[row]);
    }
}

extern "C" void kernel_launch(void* const* d_in, const int* in_sizes, int n_in,
                              void* d_out, int out_size, void* d_ws, size_t ws_size,
                              hipStream_t stream) {
    const float* enc = (const float*)d_in[0];   // (B, N, DIM) f32
    const int*   dur = (const int*)d_in[1];     // (B, N) int
    // out = expanded (B*T*DIM) ++ mask (B*T)  => out_size = B*T*(DIM+1)
    const int T = out_size / (B_ * (DIM_ + 1));

    int*   idx_map  = (int*)d_ws;               // B*T int32
    float* out      = (float*)d_out;
    float* mask_out = out + (size_t)B_ * T * DIM_;

    build_idx_kernel<<<B_, N_, 0, stream>>>(dur, idx_map, T);

    const long nf4 = (long)B_ * T * F4_PER_ROW;
    int blocks = (int)((nf4 + 255) / 256);
    if (blocks > 2048) blocks = 2048;
    expand_kernel<<<blocks, 256, 0, stream>>>(
        (const f32x4*)enc, idx_map, (f32x4*)out, mask_out, nf4);
}

// Round 4
// 58.222 us; speedup vs baseline: 1.3431x; 1.2296x over previous
//
#include <hip/hip_runtime.h>

#define B_   32
#define N_   1024
#define DIM_ 512
#define F4_PER_ROW (DIM_ / 4)   // 128

typedef float f32x4 __attribute__((ext_vector_type(4)));

// Kernel 1: per-batch inclusive scan of durations -> cum (B*N int32) in ws,
// plus the (B,T) mask output (t < total ? 1 : 0).
__global__ void scan_kernel(const int* __restrict__ durations,
                            int* __restrict__ cum,
                            float* __restrict__ mask_out, int T) {
    __shared__ int s[N_];
    const int b   = blockIdx.x;
    const int tid = threadIdx.x;
    const int d   = durations[b * N_ + tid];
    s[tid] = d;
    __syncthreads();
    for (int off = 1; off < N_; off <<= 1) {
        int v = (tid >= off) ? s[tid - off] : 0;
        __syncthreads();
        s[tid] += v;
        __syncthreads();
    }
    cum[b * N_ + tid] = s[tid];
    const int total = s[N_ - 1];
    float* mrow = mask_out + (size_t)b * T;
    for (int t = tid; t < T; t += N_) mrow[t] = (t < total) ? 1.0f : 0.0f;
}

// Kernel 2: scatter. One wave per phoneme: load the 2KB enc row once
// (sequential reads, each row read exactly once), store it d times to
// consecutive output rows. Phase B: zero the per-batch tail rows.
__global__ void scatter_kernel(const f32x4* __restrict__ enc4,
                               const int* __restrict__ cum,
                               const int* __restrict__ durations,
                               f32x4* __restrict__ out4, int T) {
    const int lane   = threadIdx.x & 63;
    const int gwave  = blockIdx.x * (blockDim.x >> 6) + (threadIdx.x >> 6);
    const int nwaves = gridDim.x * (blockDim.x >> 6);

    // Phase A: copy each phoneme row to its [cum-d, cum) output frames.
    for (int p = gwave; p < B_ * N_; p += nwaves) {
        const int d = durations[p];
        if (d == 0) continue;
        const int end = cum[p];
        const int b   = p >> 10;                 // p / N_
        const f32x4* src = enc4 + (size_t)p * F4_PER_ROW;
        const f32x4 v0 = src[lane];
        const f32x4 v1 = src[lane + 64];
        f32x4* dst = out4 + ((size_t)b * T + (end - d)) * F4_PER_ROW;
        for (int r = 0; r < d; ++r, dst += F4_PER_ROW) {
            __builtin_nontemporal_store(v0, &dst[lane]);
            __builtin_nontemporal_store(v1, &dst[lane + 64]);
        }
    }

    // Phase B: zero rows t >= total_b (wave-uniform branch).
    const f32x4 zero = {0.f, 0.f, 0.f, 0.f};
    const int nrows = B_ * T;
    for (int r = gwave; r < nrows; r += nwaves) {
        const int b = r / T;
        const int t = r - b * T;
        const int total = cum[b * N_ + N_ - 1];
        if (t >= total) {
            f32x4* dst = out4 + (size_t)r * F4_PER_ROW;
            __builtin_nontemporal_store(zero, &dst[lane]);
            __builtin_nontemporal_store(zero, &dst[lane + 64]);
        }
    }
}

extern "C" void kernel_launch(void* const* d_in, const int* in_sizes, int n_in,
                              void* d_out, int out_size, void* d_ws, size_t ws_size,
                              hipStream_t stream) {
    const float* enc = (const float*)d_in[0];   // (B, N, DIM) f32
    const int*   dur = (const int*)d_in[1];     // (B, N) int
    // out = expanded (B*T*DIM) ++ mask (B*T)  => out_size = B*T*(DIM+1)
    const int T = out_size / (B_ * (DIM_ + 1));

    int*   cum      = (int*)d_ws;               // B*N int32
    float* out      = (float*)d_out;
    float* mask_out = out + (size_t)B_ * T * DIM_;

    scan_kernel<<<B_, N_, 0, stream>>>(dur, cum, mask_out, T);
    scatter_kernel<<<2048, 256, 0, stream>>>(
        (const f32x4*)enc, cum, dur, (f32x4*)out, T);
}

// Round 5
// 57.981 us; speedup vs baseline: 1.3487x; 1.0041x over previous
//
#include <hip/hip_runtime.h>

#define B_   32
#define N_   1024
#define DIM_ 512
#define F4_PER_ROW (DIM_ / 4)   // 128

typedef float f32x4 __attribute__((ext_vector_type(4)));

// Kernel 1: per-batch inclusive scan of durations via hierarchical shfl scan
// (2 barriers total), -> cum (B*N int32) in ws, plus the (B,T) mask output.
__global__ void scan_kernel(const int* __restrict__ durations,
                            int* __restrict__ cum,
                            float* __restrict__ mask_out, int T) {
    __shared__ int wsum[16];
    const int b    = blockIdx.x;
    const int tid  = threadIdx.x;
    const int lane = tid & 63;
    const int wid  = tid >> 6;

    int x = durations[b * N_ + tid];
    // per-wave inclusive scan (6 shfl steps, no barriers)
    #pragma unroll
    for (int off = 1; off < 64; off <<= 1) {
        int v = __shfl_up(x, off, 64);
        if (lane >= off) x += v;
    }
    if (lane == 63) wsum[wid] = x;
    __syncthreads();
    // wave 0 scans the 16 wave sums
    if (wid == 0 && lane < 16) {
        int s = wsum[lane];
        #pragma unroll
        for (int off = 1; off < 16; off <<= 1) {
            int v = __shfl_up(s, off, 64);
            if (lane >= off) s += v;
        }
        wsum[lane] = s;
    }
    __syncthreads();
    x += (wid > 0) ? wsum[wid - 1] : 0;
    cum[b * N_ + tid] = x;

    const int total = wsum[15];
    float* mrow = mask_out + (size_t)b * T;
    for (int t = tid; t < T; t += N_) mrow[t] = (t < total) ? 1.0f : 0.0f;
}

// Kernel 2: scatter. One wave per phoneme: load the 2KB enc row once
// (sequential reads, each row read exactly once), store it d times to
// consecutive output rows. Phase B: zero the per-batch tail rows.
__global__ void scatter_kernel(const f32x4* __restrict__ enc4,
                               const int* __restrict__ cum,
                               const int* __restrict__ durations,
                               f32x4* __restrict__ out4, int T) {
    const int lane   = threadIdx.x & 63;
    const int gwave  = blockIdx.x * (blockDim.x >> 6) + (threadIdx.x >> 6);
    const int nwaves = gridDim.x * (blockDim.x >> 6);

    // Phase A: copy each phoneme row to its [cum-d, cum) output frames.
    for (int p = gwave; p < B_ * N_; p += nwaves) {
        const int d = durations[p];
        if (d == 0) continue;
        const int end = cum[p];
        const int b   = p >> 10;                 // p / N_
        const f32x4* src = enc4 + (size_t)p * F4_PER_ROW;
        const f32x4 v0 = src[lane];
        const f32x4 v1 = src[lane + 64];
        f32x4* dst = out4 + ((size_t)b * T + (end - d)) * F4_PER_ROW;
        for (int r = 0; r < d; ++r, dst += F4_PER_ROW) {
            __builtin_nontemporal_store(v0, &dst[lane]);
            __builtin_nontemporal_store(v1, &dst[lane + 64]);
        }
    }

    // Phase B: zero rows t >= total_b (wave-uniform branch).
    const f32x4 zero = {0.f, 0.f, 0.f, 0.f};
    const int nrows = B_ * T;
    for (int r = gwave; r < nrows; r += nwaves) {
        const int b = r / T;
        const int t = r - b * T;
        const int total = cum[b * N_ + N_ - 1];
        if (t >= total) {
            f32x4* dst = out4 + (size_t)r * F4_PER_ROW;
            __builtin_nontemporal_store(zero, &dst[lane]);
            __builtin_nontemporal_store(zero, &dst[lane + 64]);
        }
    }
}

extern "C" void kernel_launch(void* const* d_in, const int* in_sizes, int n_in,
                              void* d_out, int out_size, void* d_ws, size_t ws_size,
                              hipStream_t stream) {
    const float* enc = (const float*)d_in[0];   // (B, N, DIM) f32
    const int*   dur = (const int*)d_in[1];     // (B, N) int
    // out = expanded (B*T*DIM) ++ mask (B*T)  => out_size = B*T*(DIM+1)
    const int T = out_size / (B_ * (DIM_ + 1));

    int*   cum      = (int*)d_ws;               // B*N int32
    float* out      = (float*)d_out;
    float* mask_out = out + (size_t)B_ * T * DIM_;

    scan_kernel<<<B_, N_, 0, stream>>>(dur, cum, mask_out, T);
    scatter_kernel<<<2048, 256, 0, stream>>>(
        (const f32x4*)enc, cum, dur, (f32x4*)out, T);
}

// Round 6
// 53.617 us; speedup vs baseline: 1.4585x; 1.0814x over previous
//
#include <hip/hip_runtime.h>

#define B_   32
#define N_   1024
#define DIM_ 512
#define F4_PER_ROW (DIM_ / 4)       // 128
#define CHUNKS 64                   // blocks per batch
#define PHON_PER_CHUNK (N_ / CHUNKS) // 16

typedef float f32x4 __attribute__((ext_vector_type(4)));
typedef int   i32x4 __attribute__((ext_vector_type(4)));

// One fused kernel. 2048 blocks = 32 batches x 64 chunks. Each block:
//  1. redundantly scans its batch's 1024 durations (int4 + shfl, 2 barriers)
//  2. scatters its 16-phoneme chunk (enc row read once, stored d times, NT)
//  3. zeroes its share of the batch's tail rows
//  4. writes its slice of the batch's mask row
__global__ __launch_bounds__(256) void fused_kernel(
    const f32x4* __restrict__ enc4,
    const int*   __restrict__ dur,
    f32x4* __restrict__ out4,
    float* __restrict__ mask_out, int T)
{
    __shared__ int s_cum[N_];
    __shared__ int s_wsum[4];

    const int b     = blockIdx.x & (B_ - 1);  // batch (consecutive blocks spread batches)
    const int chunk = blockIdx.x >> 5;        // 0..63
    const int tid   = threadIdx.x;
    const int lane  = tid & 63;
    const int wid   = tid >> 6;

    // ---- block-wide inclusive scan of this batch's 1024 durations ----
    i32x4 d4 = *(const i32x4*)(dur + b * N_ + tid * 4);
    const int s0 = d4.x;
    const int s1 = s0 + d4.y;
    const int s2 = s1 + d4.z;
    const int s3 = s2 + d4.w;
    int x = s3;
    #pragma unroll
    for (int off = 1; off < 64; off <<= 1) {
        int v = __shfl_up(x, off, 64);
        if (lane >= off) x += v;
    }
    if (lane == 63) s_wsum[wid] = x;
    __syncthreads();
    int woff = 0;
    #pragma unroll
    for (int w = 0; w < 3; ++w) woff += (w < wid) ? s_wsum[w] : 0;
    const int texcl = woff + x - s3;          // exclusive prefix before this thread's 4
    s_cum[tid * 4 + 0] = texcl + s0;
    s_cum[tid * 4 + 1] = texcl + s1;
    s_cum[tid * 4 + 2] = texcl + s2;
    s_cum[tid * 4 + 3] = texcl + s3;
    __syncthreads();
    const int total = s_cum[N_ - 1];

    // ---- scatter the 16 phonemes of this chunk (4 per wave) ----
    const int pbase = chunk * PHON_PER_CHUNK;
    for (int k = wid; k < PHON_PER_CHUNK; k += 4) {
        const int p     = pbase + k;
        const int end   = s_cum[p];
        const int start = (p == 0) ? 0 : s_cum[p - 1];
        const int d     = end - start;
        if (d == 0) continue;
        const f32x4* src = enc4 + ((size_t)b * N_ + p) * F4_PER_ROW;
        const f32x4 v0 = src[lane];
        const f32x4 v1 = src[lane + 64];
        f32x4* dst = out4 + ((size_t)b * T + start) * F4_PER_ROW;
        for (int r = 0; r < d; ++r, dst += F4_PER_ROW) {
            __builtin_nontemporal_store(v0, &dst[lane]);
            __builtin_nontemporal_store(v1, &dst[lane + 64]);
        }
    }

    // ---- zero tail rows (distributed over this batch's 256 waves) ----
    const f32x4 zero = {0.f, 0.f, 0.f, 0.f};
    for (int t = total + chunk * 4 + wid; t < T; t += CHUNKS * 4) {
        f32x4* dst = out4 + ((size_t)b * T + t) * F4_PER_ROW;
        __builtin_nontemporal_store(zero, &dst[lane]);
        __builtin_nontemporal_store(zero, &dst[lane + 64]);
    }

    // ---- mask row (distributed over this batch's 64 blocks) ----
    float* mrow = mask_out + (size_t)b * T;
    for (int t = chunk * 256 + tid; t < T; t += CHUNKS * 256) {
        mrow[t] = (t < total) ? 1.0f : 0.0f;
    }
}

extern "C" void kernel_launch(void* const* d_in, const int* in_sizes, int n_in,
                              void* d_out, int out_size, void* d_ws, size_t ws_size,
                              hipStream_t stream) {
    const float* enc = (const float*)d_in[0];   // (B, N, DIM) f32
    const int*   dur = (const int*)d_in[1];     // (B, N) int
    // out = expanded (B*T*DIM) ++ mask (B*T)  => out_size = B*T*(DIM+1)
    const int T = out_size / (B_ * (DIM_ + 1));

    float* out      = (float*)d_out;
    float* mask_out = out + (size_t)B_ * T * DIM_;

    fused_kernel<<<B_ * CHUNKS, 256, 0, stream>>>(
        (const f32x4*)enc, dur, (f32x4*)out, mask_out, T);
}

// Round 7
// 52.337 us; speedup vs baseline: 1.4942x; 1.0245x over previous
//
#include <hip/hip_runtime.h>

#define B_   32
#define N_   1024
#define DIM_ 512
#define F4_PER_ROW (DIM_ / 4)        // 128
#define CHUNKS 128                   // blocks per batch (2x oversubscribed grid)
#define PHON_PER_CHUNK (N_ / CHUNKS) // 8

typedef float f32x4 __attribute__((ext_vector_type(4)));
typedef int   i32x4 __attribute__((ext_vector_type(4)));

// One fused kernel. 4096 blocks = 32 batches x 128 chunks. Each block:
//  1. redundantly scans its batch's 1024 durations (int4 + shfl, 2 barriers)
//  2. scatters its 8-phoneme chunk (enc row read once, stored d times, NT)
//  3. zeroes its share of the batch's tail rows
//  4. writes its slice of the batch's mask row
// Grid is 2x the resident-block count so the dispatcher backfills CUs whose
// blocks finish early (random per-chunk work, sigma/mu ~ 22% at 8 phonemes).
__global__ __launch_bounds__(256) void fused_kernel(
    const f32x4* __restrict__ enc4,
    const int*   __restrict__ dur,
    f32x4* __restrict__ out4,
    float* __restrict__ mask_out, int T)
{
    __shared__ int s_cum[N_];
    __shared__ int s_wsum[4];

    const int b     = blockIdx.x & (B_ - 1);  // batch (low bits -> batches spread)
    const int chunk = blockIdx.x >> 5;        // 0..CHUNKS-1
    const int tid   = threadIdx.x;
    const int lane  = tid & 63;
    const int wid   = tid >> 6;

    // ---- block-wide inclusive scan of this batch's 1024 durations ----
    i32x4 d4 = *(const i32x4*)(dur + b * N_ + tid * 4);
    const int s0 = d4.x;
    const int s1 = s0 + d4.y;
    const int s2 = s1 + d4.z;
    const int s3 = s2 + d4.w;
    int x = s3;
    #pragma unroll
    for (int off = 1; off < 64; off <<= 1) {
        int v = __shfl_up(x, off, 64);
        if (lane >= off) x += v;
    }
    if (lane == 63) s_wsum[wid] = x;
    __syncthreads();
    int woff = 0;
    #pragma unroll
    for (int w = 0; w < 3; ++w) woff += (w < wid) ? s_wsum[w] : 0;
    const int texcl = woff + x - s3;          // exclusive prefix before this thread's 4
    s_cum[tid * 4 + 0] = texcl + s0;
    s_cum[tid * 4 + 1] = texcl + s1;
    s_cum[tid * 4 + 2] = texcl + s2;
    s_cum[tid * 4 + 3] = texcl + s3;
    __syncthreads();
    const int total = s_cum[N_ - 1];

    // ---- scatter the 8 phonemes of this chunk (2 per wave) ----
    const int pbase = chunk * PHON_PER_CHUNK;
    for (int k = wid; k < PHON_PER_CHUNK; k += 4) {
        const int p     = pbase + k;
        const int end   = s_cum[p];
        const int start = (p == 0) ? 0 : s_cum[p - 1];
        const int d     = end - start;
        if (d == 0) continue;
        const f32x4* src = enc4 + ((size_t)b * N_ + p) * F4_PER_ROW;
        const f32x4 v0 = src[lane];
        const f32x4 v1 = src[lane + 64];
        f32x4* dst = out4 + ((size_t)b * T + start) * F4_PER_ROW;
        for (int r = 0; r < d; ++r, dst += F4_PER_ROW) {
            __builtin_nontemporal_store(v0, &dst[lane]);
            __builtin_nontemporal_store(v1, &dst[lane + 64]);
        }
    }

    // ---- zero tail rows (distributed over this batch's CHUNKS*4 waves) ----
    const f32x4 zero = {0.f, 0.f, 0.f, 0.f};
    for (int t = total + chunk * 4 + wid; t < T; t += CHUNKS * 4) {
        f32x4* dst = out4 + ((size_t)b * T + t) * F4_PER_ROW;
        __builtin_nontemporal_store(zero, &dst[lane]);
        __builtin_nontemporal_store(zero, &dst[lane + 64]);
    }

    // ---- mask row (distributed over this batch's CHUNKS blocks) ----
    float* mrow = mask_out + (size_t)b * T;
    for (int t = chunk * 256 + tid; t < T; t += CHUNKS * 256) {
        mrow[t] = (t < total) ? 1.0f : 0.0f;
    }
}

extern "C" void kernel_launch(void* const* d_in, const int* in_sizes, int n_in,
                              void* d_out, int out_size, void* d_ws, size_t ws_size,
                              hipStream_t stream) {
    const float* enc = (const float*)d_in[0];   // (B, N, DIM) f32
    const int*   dur = (const int*)d_in[1];     // (B, N) int
    // out = expanded (B*T*DIM) ++ mask (B*T)  => out_size = B*T*(DIM+1)
    const int T = out_size / (B_ * (DIM_ + 1));

    float* out      = (float*)d_out;
    float* mask_out = out + (size_t)B_ * T * DIM_;

    fused_kernel<<<B_ * CHUNKS, 256, 0, stream>>>(
        (const f32x4*)enc, dur, (f32x4*)out, mask_out, T);
}